// Round 8
// baseline (111.748 us; speedup 1.0000x reference)
//
#include <hip/hip_runtime.h>

// Chamfer loss: pred (2048,8,3) vs gt (2048,8,3) fp32. N=16384 pts/side.
// out = mean(min_m d) + mean(min_n d); 8-corner group-mean == global mean.
//
// R11: spill-PROOF variant. R8 evidence: allocator squeezed to 64 VGPR
// (8 waves/EU heuristic) despite a 128 budget and spilled ~35 regs;
// neither launch_bounds min-waves (lower bound only) nor waves_per_eu
// reliably forbids the squeeze. Structural fix: peak demand ~50 VGPR
// (bfr[4]=16 + cmax[4] + afc 4 + rmax 4 + transients 8 + addr ~12) so
// ANY allocation >=64 is spill-free.
//  - YW 128->64 (4 y-tiles in 16 VGPR); grid (64,64)=4096 blocks,
//    XCD pin yc%8 intact; 20KB LDS -> 8 blocks/CU (32 waves/CU TLP).
//  - partials now 64 row + 64 col slices (8MB); reduce symmetric.
//  - everything else is the verified R10 structure: bf16 3-way-split
//    bidirectional MFMA (absmax 0.0 since R5), A-chunk in LDS,
//    DPP ror-max row flush, shfl col flush, block-combined rowacc,
//    coalesced partial stores, no atomics in hot path.
// Fixed per round: 268MB ws re-poison fill ~40us + ~10us launch gaps.
// Falsification: if total stays >=90us, spill theory is dead -> pivot.

#define NPTS   16384
#define BLOCK  256            // 4 waves
#define XCH    256            // x-points per block (16 tiles, 16KB packed)
#define NXC    (NPTS / XCH)   // 64
#define YW     64             // y-points per wave (4 tiles in 16 VGPR)
#define YCH    (4 * YW)       // 256 y-points per block
#define NYC    (NPTS / YCH)   // 64
#define ONEBF  0x3F80         // bf16 1.0

// ws: [0,1MB) Ppa | [1,2MB) Pgb | [2MB,10MB) part[128][NPTS] f32
//   slices 0..63   = row partials (pred mins), id = yc (block-combined)
//   slices 64..127 = col partials (gt mins),   id = 64+xb
#define WS_PGB  (1u << 20)
#define WS_PART (2u << 20)
#define NROWSL  NYC           // 64
#define NCOLSL  NXC           // 64

typedef __attribute__((ext_vector_type(8))) short bf16x8;
typedef __attribute__((ext_vector_type(4))) float f32x4;

__device__ inline unsigned short f2bf(float f) {  // fp32 -> bf16 RNE
    unsigned int u = __float_as_uint(f);
    return (unsigned short)((u + 0x7FFFu + ((u >> 16) & 1u)) >> 16);
}
__device__ inline float bf2f(unsigned short h) {
    return __uint_as_float((unsigned int)h << 16);
}
__device__ inline void split3(float v, unsigned short* s) {
    unsigned short h = f2bf(v);  float r = v - bf2f(h);
    unsigned short m = f2bf(r);  r -= bf2f(m);
    s[0] = h; s[1] = m; s[2] = f2bf(r);
}

// K-slot map (identical order on A and B rows => lane->K bijection cancels):
//   s=c*3+d, c<6: cross combos (i,j)=(h,h)(h,m)(m,h)(h,l)(m,m)(l,h)
//   s=18..20: a=split3(-|p|^2/2), b=1 ; s=21..23: a=1, b=split3(-|p|^2/2)
//   s=24..31: 0   => S[r][c] = x.y - |x|^2/2 - |y|^2/2 = -d2/2
__device__ inline void build_rows(const float p[3], unsigned short* a,
                                  unsigned short* b) {
    const int CI[6] = {0, 0, 1, 0, 1, 2};
    const int CJ[6] = {0, 1, 0, 2, 1, 0};
    unsigned short xs[3][3], nn[3], t[3];
#pragma unroll
    for (int d = 0; d < 3; ++d) {
        split3(p[d], t);
        xs[0][d] = t[0]; xs[1][d] = t[1]; xs[2][d] = t[2];
    }
    split3(-0.5f * (p[0]*p[0] + p[1]*p[1] + p[2]*p[2]), nn);
#pragma unroll
    for (int c = 0; c < 6; ++c)
#pragma unroll
        for (int d = 0; d < 3; ++d) {
            a[c*3+d] = xs[CI[c]][d];
            b[c*3+d] = xs[CJ[c]][d];
        }
#pragma unroll
    for (int k = 0; k < 3; ++k) {
        a[18+k] = nn[k];  b[18+k] = ONEBF;
        a[21+k] = ONEBF;  b[21+k] = nn[k];
    }
#pragma unroll
    for (int k = 24; k < 32; ++k) { a[k] = 0; b[k] = 0; }
}

__device__ inline void store_row(unsigned short* dst, const unsigned short* s) {
    unsigned int w[16];
#pragma unroll
    for (int k = 0; k < 16; ++k)
        w[k] = (unsigned int)s[2*k] | ((unsigned int)s[2*k+1] << 16);
    uint4* d4 = reinterpret_cast<uint4*>(dst);
#pragma unroll
    for (int k = 0; k < 4; ++k)
        d4[k] = make_uint4(w[4*k], w[4*k+1], w[4*k+2], w[4*k+3]);
}

__global__ __launch_bounds__(256) void pack_points(
        const float* __restrict__ pred, const float* __restrict__ gt,
        unsigned short* __restrict__ Ppa, unsigned short* __restrict__ Pgb,
        float* __restrict__ out) {
    const int i = blockIdx.x * 256 + threadIdx.x;
    if (i == 0) out[0] = 0.0f;  // replaces a memset dispatch
    if (i >= NPTS) return;
    float p[3] = {pred[3*i], pred[3*i+1], pred[3*i+2]};
    float q[3] = {gt[3*i],   gt[3*i+1],   gt[3*i+2]};
    unsigned short ra[32], rb[32];
    build_rows(p, ra, rb);
    store_row(Ppa + (size_t)i * 32, ra);   // pred used as A (rows)
    build_rows(q, ra, rb);
    store_row(Pgb + (size_t)i * 32, rb);   // gt used as B (cols)
}

// DPP rotate-max within 16-lane rows (VALU pipe; verified R6-R10).
template <int CTRL>
__device__ inline float rormax(float v) {
    int t = __builtin_amdgcn_update_dpp(0, __float_as_int(v), CTRL, 0xF, 0xF,
                                        false);
    return fmaxf(v, __int_as_float(t));
}

__global__ __launch_bounds__(BLOCK) void chamfer_bidi(
        const unsigned short* __restrict__ Ppa,
        const unsigned short* __restrict__ Pgb,
        float* __restrict__ part) {
    const int yc = blockIdx.x;   // fastest-varying -> XCD = yc % 8 (B pin)
    const int xb = blockIdx.y;
    const int tid = threadIdx.x;
    const int lane = tid & 63, w = tid >> 6;
    const int col = lane & 15, kg = lane >> 4;
    const int xbase = xb * XCH;
    const int ybase = yc * YCH + w * YW;

    __shared__ __align__(16) unsigned short Ash[XCH * 32];  // 16 KB packed A
    __shared__ float rowacc[4][XCH];                        // 4 KB

    // stage A-chunk: 4 x 4KB fully-contiguous copies
    {
        const uint4* src = reinterpret_cast<const uint4*>(Ppa + (size_t)xbase * 32);
        uint4* dst = reinterpret_cast<uint4*>(Ash);
#pragma unroll
        for (int j = 0; j < 4; ++j)
            dst[j * 256 + tid] = src[j * 256 + tid];
    }

    // B-frags (wave's 64 y) resident in 16 VGPRs; each load instruction
    // covers a contiguous 1KB per wave -> coalesced
    bf16x8 bfr[4];
#pragma unroll
    for (int yt = 0; yt < 4; ++yt)
        bfr[yt] = *reinterpret_cast<const bf16x8*>(
            Pgb + (size_t)(ybase + yt * 16 + col) * 32 + kg * 8);

    float cmax[4];
#pragma unroll
    for (int yt = 0; yt < 4; ++yt) cmax[yt] = -3.0e38f;

    const f32x4 z4 = {0.0f, 0.0f, 0.0f, 0.0f};

    __syncthreads();  // Ash ready

#pragma unroll 1
    for (int xt = 0; xt < 16; ++xt) {
        // A-frag straight from LDS; contiguous-1KB wave pattern
        bf16x8 afc = *reinterpret_cast<const bf16x8*>(
            Ash + (xt * 16 + col) * 32 + kg * 8);

        f32x4 rmax = {-3.0e38f, -3.0e38f, -3.0e38f, -3.0e38f};
#pragma unroll
        for (int yt = 0; yt < 4; yt += 2) {
            f32x4 A = __builtin_amdgcn_mfma_f32_16x16x32_bf16(afc, bfr[yt],     z4, 0, 0, 0);
            f32x4 B = __builtin_amdgcn_mfma_f32_16x16x32_bf16(afc, bfr[yt + 1], z4, 0, 0, 0);
            // row-merge: 4 v_max3 per MFMA pair
            rmax.x = fmaxf(fmaxf(A.x, B.x), rmax.x);
            rmax.y = fmaxf(fmaxf(A.y, B.y), rmax.y);
            rmax.z = fmaxf(fmaxf(A.z, B.z), rmax.z);
            rmax.w = fmaxf(fmaxf(A.w, B.w), rmax.w);
            // col-merge: 2 v_max3 per MFMA
            float ta = fmaxf(fmaxf(A.x, A.y), A.z);
            cmax[yt]     = fmaxf(fmaxf(ta, A.w), cmax[yt]);
            float tb = fmaxf(fmaxf(B.x, B.y), B.z);
            cmax[yt + 1] = fmaxf(fmaxf(tb, B.w), cmax[yt + 1]);
        }

        // row flush -> LDS accumulator (coalesced global store at the end)
#pragma unroll
        for (int i = 0; i < 4; ++i) {
            float v = rmax[i];
            v = rormax<0x121>(v);
            v = rormax<0x122>(v);
            v = rormax<0x124>(v);
            v = rormax<0x128>(v);
            if (col == 0)
                rowacc[w][xt * 16 + kg * 4 + i] = fmaxf(-2.0f * v, 0.0f);
        }
    }

    // col flush: reduce across the 4 row-groups; 64B-contiguous stores
#pragma unroll
    for (int yt = 0; yt < 4; ++yt) {
        float v = cmax[yt];
        v = fmaxf(v, __shfl_xor(v, 16, 64));
        v = fmaxf(v, __shfl_xor(v, 32, 64));
        if (kg == 0)
            part[(size_t)(NROWSL + xb) * NPTS + ybase + yt * 16 + col] =
                fmaxf(-2.0f * v, 0.0f);
    }

    // row-min partials: min-combine the 4 waves in-block -> ONE slice/yc,
    // full-line coalesced store
    __syncthreads();  // rowacc complete across waves
    float m = fminf(fminf(rowacc[0][tid], rowacc[1][tid]),
                    fminf(rowacc[2][tid], rowacc[3][tid]));
    part[(size_t)yc * NPTS + xbase + tid] = m;
}

__global__ __launch_bounds__(256) void chamfer_reduce(
        const float* __restrict__ part, float* __restrict__ out) {
    const int gid = blockIdx.x * 256 + threadIdx.x;  // 32 blocks x 256
    const int side = gid >> 12;                      // 4096 f32x4 per side
    const int idx4 = (gid & 4095) * 4;
    const int off  = side * NROWSL;
    float4 m = make_float4(3.0e38f, 3.0e38f, 3.0e38f, 3.0e38f);
#pragma unroll 8
    for (int c = 0; c < 64; ++c) {
        float4 v = *reinterpret_cast<const float4*>(
            part + (size_t)(off + c) * NPTS + idx4);
        m.x = fminf(m.x, v.x); m.y = fminf(m.y, v.y);
        m.z = fminf(m.z, v.z); m.w = fminf(m.w, v.w);
    }
    float s = sqrtf(m.x) + sqrtf(m.y) + sqrtf(m.z) + sqrtf(m.w);
#pragma unroll
    for (int o = 32; o > 0; o >>= 1)
        s += __shfl_down(s, o, 64);
    if ((threadIdx.x & 63) == 0)
        atomicAdd(out, s * (1.0f / (float)NPTS));
}

extern "C" void kernel_launch(void* const* d_in, const int* in_sizes, int n_in,
                              void* d_out, int out_size, void* d_ws, size_t ws_size,
                              hipStream_t stream) {
    const float* pred = (const float*)d_in[0];
    const float* gt   = (const float*)d_in[1];
    float* out        = (float*)d_out;
    unsigned short* Ppa = (unsigned short*)d_ws;
    unsigned short* Pgb = (unsigned short*)((char*)d_ws + WS_PGB);
    float* part         = (float*)((char*)d_ws + WS_PART);

    hipLaunchKernelGGL(pack_points, dim3(NPTS / 256), dim3(256), 0, stream,
                       pred, gt, Ppa, Pgb, out);
    hipLaunchKernelGGL(chamfer_bidi, dim3(NYC, NXC), dim3(BLOCK), 0, stream,
                       Ppa, Pgb, part);
    hipLaunchKernelGGL(chamfer_reduce, dim3(2 * NPTS / 1024), dim3(256), 0, stream,
                       part, out);
}